// Round 3
// baseline (242.896 us; speedup 1.0000x reference)
//
#include <hip/hip_runtime.h>
#include <hip/hip_bf16.h>
#include <stdint.h>

// Problem: X = fm_t reshaped [N=1024, D=16384] fp32.
// loss = mean_{i,j} ((sq_i + sq_j - 2*g_ij)/D)^2,  g = X X^T, sq_i = |x_i|^2.
// Symmetric: only upper-triangle 128x128 tiles (36 of 64), off-diag weighted x2.
#define N_ROWS 1024
#define KDIM   16384
#define SPLITK 32
#define KBLK   (KDIM / SPLITK)   // 512
#define BK     32
#define NITER  (KBLK / BK)       // 16

typedef __attribute__((ext_vector_type(8))) __bf16 bf16x8;
typedef __attribute__((ext_vector_type(4))) float  f32x4;

#define GLOBAL_AS __attribute__((address_space(1)))
#define LDS_AS    __attribute__((address_space(3)))

// s_waitcnt imm: vmcnt[3:0]=bits3:0, expcnt=bits6:4(max=7), lgkmcnt=bits11:8
// (max=15), vmcnt[5:4]=bits15:14. Wait ONLY on vmcnt<=N: 0x0F70 | N.
#define WAITCNT_VM(N) __builtin_amdgcn_s_waitcnt(0x0F70 | (N))

__device__ __forceinline__ void block_barrier() {
    // raw barrier: NO implicit vmcnt(0) drain (unlike __syncthreads()).
    // asm memory clobbers stop the compiler moving LDS/global ops across it.
    asm volatile("" ::: "memory");
    __builtin_amdgcn_s_barrier();
    asm volatile("" ::: "memory");
}

// Upper-triangle tile enumeration: t -> (ti, tj), ti <= tj, 8x8 tile grid.
__device__ __constant__ unsigned char T_I[36] = {
    0,0,0,0,0,0,0,0, 1,1,1,1,1,1,1, 2,2,2,2,2,2, 3,3,3,3,3, 4,4,4,4, 5,5,5, 6,6, 7};
__device__ __constant__ unsigned char T_J[36] = {
    0,1,2,3,4,5,6,7, 1,2,3,4,5,6,7, 2,3,4,5,6,7, 3,4,5,6,7, 4,5,6,7, 5,6,7, 6,7, 7};

__device__ __forceinline__ unsigned short f32_to_bf16_rne(float f) {
    unsigned int u = __float_as_uint(f);
    unsigned int lsb = (u >> 16) & 1u;
    u += 0x7fffu + lsb;
    return (unsigned short)(u >> 16);
}

// Kernel 1: fused fp32->bf16 cast of X plus exact fp32 row norms sq[i].
__global__ __launch_bounds__(256) void cast_sq_kernel(
        const float* __restrict__ X, unsigned short* __restrict__ Xb,
        float* __restrict__ sq) {
    const int row = blockIdx.x;
    const float4* src = (const float4*)(X + (size_t)row * KDIM);
    uint2* dst = (uint2*)(Xb + (size_t)row * KDIM);
    float ss = 0.f;
#pragma unroll
    for (int c = 0; c < 16; ++c) {
        int idx = c * 256 + threadIdx.x;
        float4 v = src[idx];
        ss += v.x * v.x + v.y * v.y + v.z * v.z + v.w * v.w;
        uint2 p;
        p.x = (unsigned int)f32_to_bf16_rne(v.x) | ((unsigned int)f32_to_bf16_rne(v.y) << 16);
        p.y = (unsigned int)f32_to_bf16_rne(v.z) | ((unsigned int)f32_to_bf16_rne(v.w) << 16);
        dst[idx] = p;
    }
#pragma unroll
    for (int o = 32; o; o >>= 1) ss += __shfl_down(ss, o, 64);
    __shared__ float red[4];
    int lane = threadIdx.x & 63, wv = threadIdx.x >> 6;
    if (lane == 0) red[wv] = ss;
    __syncthreads();
    if (threadIdx.x == 0) sq[row] = red[0] + red[1] + red[2] + red[3];
}

// Kernel 2: pipelined split-K bf16 Gram GEMM, upper-triangle tiles.
// BM=BN=128, BK=32, depth-1 double-buffered global_load_lds staging with raw
// s_barrier + s_waitcnt vmcnt(4): iter k+1's loads stay in flight while iter k
// computes (the __syncthreads() vmcnt(0) drain was the latency bottleneck).
// LDS layout per phase: A[128][32] then B[128][32]; 16B chunk j of row r is
// stored at slot j ^ ((r>>1)&3) (conflict-free b128 reads).
__global__ __launch_bounds__(256, 4) void gram_gemm_kernel(
        const unsigned short* __restrict__ Xb, float* __restrict__ G) {
    __shared__ unsigned short SH[2 * 8192];  // 2 phases x (A 8KB + B 8KB)

    const int ti = T_I[blockIdx.x];
    const int tj = T_J[blockIdx.x];
    const int row0 = ti * 128;
    const int col0 = tj * 128;
    const int kbeg = blockIdx.y * KBLK;

    const int tid  = threadIdx.x;
    const int lane = tid & 63;
    const int wv   = tid >> 6;
    const int wm   = (wv >> 1) * 64;
    const int wn   = (wv & 1) * 64;
    const int lr   = lane & 15;
    const int lq   = lane >> 4;          // k-chunk 0..3
    const int soff = (lq ^ ((lr >> 1) & 3)) * 8;  // swizzled slot, in shorts

    // staging: 512 chunks/array, 2 per thread per array
    int c0 = tid, c1 = 256 + tid;
    int r0s = c0 >> 2, j0 = c0 & 3, js0 = j0 ^ ((r0s >> 1) & 3);
    int r1s = c1 >> 2, j1 = c1 & 3, js1 = j1 ^ ((r1s >> 1) & 3);
    const unsigned short* gA0 = Xb + (size_t)(row0 + r0s) * KDIM + kbeg + js0 * 8;
    const unsigned short* gA1 = Xb + (size_t)(row0 + r1s) * KDIM + kbeg + js1 * 8;
    const unsigned short* gB0 = Xb + (size_t)(col0 + r0s) * KDIM + kbeg + js0 * 8;
    const unsigned short* gB1 = Xb + (size_t)(col0 + r1s) * KDIM + kbeg + js1 * 8;

    f32x4 acc[4][4] = {};

#define STAGE(ph, kk)                                                          \
    do {                                                                       \
        unsigned short* b = &SH[(ph) * 8192];                                  \
        __builtin_amdgcn_global_load_lds((GLOBAL_AS void*)(void*)(gA0 + (kk)), \
                                         (LDS_AS void*)&b[c0 * 8], 16, 0, 0);  \
        __builtin_amdgcn_global_load_lds((GLOBAL_AS void*)(void*)(gB0 + (kk)), \
                                         (LDS_AS void*)&b[4096 + c0 * 8], 16, 0, 0); \
        __builtin_amdgcn_global_load_lds((GLOBAL_AS void*)(void*)(gA1 + (kk)), \
                                         (LDS_AS void*)&b[c1 * 8], 16, 0, 0);  \
        __builtin_amdgcn_global_load_lds((GLOBAL_AS void*)(void*)(gB1 + (kk)), \
                                         (LDS_AS void*)&b[4096 + c1 * 8], 16, 0, 0); \
    } while (0)

    STAGE(0, 0);
    int phase = 0;
#pragma unroll 4
    for (int k = 1; k <= NITER; ++k) {
        if (k < NITER) {
            STAGE(phase ^ 1, k * BK);
            WAITCNT_VM(4);   // oldest 4 (current phase) landed; 4 stay in flight
        } else {
            WAITCNT_VM(0);
        }
        block_barrier();     // all waves' current-phase loads complete

        const unsigned short* b = &SH[phase * 8192];
        bf16x8 af[4], bq[4];
#pragma unroll
        for (int i = 0; i < 4; ++i)
            af[i] = *(const bf16x8*)&b[(wm + i * 16 + lr) * 32 + soff];
#pragma unroll
        for (int j = 0; j < 4; ++j)
            bq[j] = *(const bf16x8*)&b[4096 + (wn + j * 16 + lr) * 32 + soff];
#pragma unroll
        for (int i = 0; i < 4; ++i)
#pragma unroll
            for (int j = 0; j < 4; ++j)
                acc[i][j] = __builtin_amdgcn_mfma_f32_16x16x32_bf16(
                    af[i], bq[j], acc[i][j], 0, 0, 0);

        block_barrier();     // all waves done reading this phase before overwrite
        phase ^= 1;
    }
#undef STAGE

    // epilogue: C/D layout col=lane&15, row=(lane>>4)*4+reg
    const int crow0 = row0 + wm + lq * 4;
    const int ccol0 = col0 + wn + lr;
#pragma unroll
    for (int i = 0; i < 4; ++i)
#pragma unroll
        for (int j = 0; j < 4; ++j)
#pragma unroll
            for (int r = 0; r < 4; ++r) {
                int grow = crow0 + i * 16 + r;
                int gcol = ccol0 + j * 16;
                atomicAdd(&G[(size_t)grow * N_ROWS + gcol], acc[i][j][r]);
            }
}

// Kernel 3: loss = (1/N^2) * sum over upper tiles of w * ((sq_i+sq_j-2g)/D)^2
__global__ __launch_bounds__(256) void loss_kernel(
        const float* __restrict__ G, const float* __restrict__ sq,
        float* __restrict__ out) {
    const float invD = 1.0f / (float)KDIM;
    const int TOT = 36 * 128 * 128;
    float acc = 0.f;
    for (int u = blockIdx.x * 256 + threadIdx.x; u < TOT; u += gridDim.x * 256) {
        int t = u >> 14;
        int e = u & 16383;
        int i = T_I[t] * 128 + (e >> 7);
        int j = T_J[t] * 128 + (e & 127);
        float g = G[i * N_ROWS + j];
        float v = (sq[i] + sq[j] - 2.0f * g) * invD;
        float w = (T_I[t] == T_J[t]) ? 1.0f : 2.0f;
        acc += w * v * v;
    }
#pragma unroll
    for (int o = 32; o; o >>= 1) acc += __shfl_down(acc, o, 64);
    __shared__ float red[4];
    int lane = threadIdx.x & 63, wv = threadIdx.x >> 6;
    if (lane == 0) red[wv] = acc;
    __syncthreads();
    if (threadIdx.x == 0) {
        float total = red[0] + red[1] + red[2] + red[3];
        atomicAdd(out, total * (1.0f / ((float)N_ROWS * (float)N_ROWS)));
    }
}

extern "C" void kernel_launch(void* const* d_in, const int* in_sizes, int n_in,
                              void* d_out, int out_size, void* d_ws, size_t ws_size,
                              hipStream_t stream) {
    // d_in[0] = fm_s (dead per reference bug), d_in[1] = fm_t
    const float* fm_t = (const float*)d_in[1];
    float* out = (float*)d_out;

    // Workspace: Xb bf16 [32 MB] | G fp32 [4 MB] | sq fp32 [4 KB]
    char* ws = (char*)d_ws;
    unsigned short* Xb = (unsigned short*)ws;
    float* G  = (float*)(ws + (size_t)N_ROWS * KDIM * 2);
    float* sq = (float*)(ws + (size_t)N_ROWS * KDIM * 2 + (size_t)N_ROWS * N_ROWS * 4);

    hipMemsetAsync(G, 0, (size_t)N_ROWS * N_ROWS * sizeof(float), stream);
    hipMemsetAsync(out, 0, sizeof(float), stream);

    cast_sq_kernel<<<dim3(N_ROWS), 256, 0, stream>>>(fm_t, Xb, sq);
    gram_gemm_kernel<<<dim3(36, SPLITK), 256, 0, stream>>>(Xb, G);
    loss_kernel<<<dim3(256), 256, 0, stream>>>(G, sq, out);
}

// Round 4
// 189.561 us; speedup vs baseline: 1.2814x; 1.2814x over previous
//
#include <hip/hip_runtime.h>
#include <hip/hip_bf16.h>
#include <stdint.h>

// Problem: X = fm_t reshaped [N=1024, D=16384] fp32.
// loss = mean_{i,j} ((sq_i + sq_j - 2*g_ij)/D)^2,  g = X X^T, sq_i = |x_i|^2.
// Symmetric: only upper-triangle 128x128 tiles (36 of 64), off-diag weight x2.
#define N_ROWS 1024
#define KDIM   16384
#define SPLITK 16
#define KBLK   (KDIM / SPLITK)   // 1024
#define BK     32
#define NITER  (KBLK / BK)       // 32

typedef __attribute__((ext_vector_type(8))) __bf16 bf16x8;
typedef __attribute__((ext_vector_type(4))) float  f32x4;

#define GLOBAL_AS __attribute__((address_space(1)))
#define LDS_AS    __attribute__((address_space(3)))

// s_waitcnt imm: vmcnt[3:0]=bits3:0, expcnt=bits6:4, lgkmcnt=bits11:8,
// vmcnt[5:4]=bits15:14. Wait ONLY on vmcnt<=N (N<16): 0x0F70 | N.
#define WAITCNT_VM(N) __builtin_amdgcn_s_waitcnt(0x0F70 | (N))

__device__ __forceinline__ void block_barrier() {
    asm volatile("" ::: "memory");
    __builtin_amdgcn_s_barrier();   // raw: no implicit vmcnt(0) drain
    asm volatile("" ::: "memory");
}

// Upper-triangle tile enumeration: t -> (ti, tj), ti <= tj, 8x8 tile grid.
__device__ __constant__ unsigned char T_I[36] = {
    0,0,0,0,0,0,0,0, 1,1,1,1,1,1,1, 2,2,2,2,2,2, 3,3,3,3,3, 4,4,4,4, 5,5,5, 6,6, 7};
__device__ __constant__ unsigned char T_J[36] = {
    0,1,2,3,4,5,6,7, 1,2,3,4,5,6,7, 2,3,4,5,6,7, 3,4,5,6,7, 4,5,6,7, 5,6,7, 6,7, 7};

__device__ __forceinline__ unsigned short f32_to_bf16_rne(float f) {
    unsigned int u = __float_as_uint(f);
    unsigned int lsb = (u >> 16) & 1u;
    u += 0x7fffu + lsb;
    return (unsigned short)(u >> 16);
}

// Kernel 1: fused fp32->bf16 cast of X plus exact fp32 row norms sq[i].
__global__ __launch_bounds__(256) void cast_sq_kernel(
        const float* __restrict__ X, unsigned short* __restrict__ Xb,
        float* __restrict__ sq) {
    const int row = blockIdx.x;
    const float4* src = (const float4*)(X + (size_t)row * KDIM);
    uint2* dst = (uint2*)(Xb + (size_t)row * KDIM);
    float ss = 0.f;
#pragma unroll
    for (int c = 0; c < 16; ++c) {
        int idx = c * 256 + threadIdx.x;
        float4 v = src[idx];
        ss += v.x * v.x + v.y * v.y + v.z * v.z + v.w * v.w;
        uint2 p;
        p.x = (unsigned int)f32_to_bf16_rne(v.x) | ((unsigned int)f32_to_bf16_rne(v.y) << 16);
        p.y = (unsigned int)f32_to_bf16_rne(v.z) | ((unsigned int)f32_to_bf16_rne(v.w) << 16);
        dst[idx] = p;
    }
#pragma unroll
    for (int o = 32; o; o >>= 1) ss += __shfl_down(ss, o, 64);
    __shared__ float red[4];
    int lane = threadIdx.x & 63, wv = threadIdx.x >> 6;
    if (lane == 0) red[wv] = ss;
    __syncthreads();
    if (threadIdx.x == 0) sq[row] = red[0] + red[1] + red[2] + red[3];
}

// Kernel 2: depth-3 pipelined split-K bf16 Gram GEMM, upper-triangle tiles.
// BM=BN=128, BK=32, 3 LDS stages (48 KB -> 3 blocks/CU). Stage k+3 issued at
// iter k => ~3 iterations of latency lead; raw s_barrier + s_waitcnt vmcnt(8)
// (never a mid-loop vmcnt(0) drain). Epilogue: PLAIN bf16 partial stores (no
// atomics); loss kernel folds the split-sum.
// LDS per stage: A[128][32] then B[128][32]; 16B chunk j of row r stored at
// slot j ^ ((r>>1)&3): every bank-quad exactly 2-way on ds_read_b128 (free).
__global__ __launch_bounds__(256) void gram_gemm_kernel(
        const unsigned short* __restrict__ Xb, unsigned short* __restrict__ P) {
    __shared__ unsigned short SH[3 * 8192];  // 3 stages x (A 8KB + B 8KB)

    const int ti = T_I[blockIdx.x];
    const int tj = T_J[blockIdx.x];
    const int row0 = ti * 128;
    const int col0 = tj * 128;
    const int kbeg = blockIdx.y * KBLK;

    const int tid  = threadIdx.x;
    const int lane = tid & 63;
    const int wv   = tid >> 6;
    const int wm   = (wv >> 1) * 64;
    const int wn   = (wv & 1) * 64;
    const int lr   = lane & 15;
    const int lq   = lane >> 4;                    // k-chunk 0..3
    const int soff = (lq ^ ((lr >> 1) & 3)) * 8;   // swizzled slot (shorts)

    // staging geometry: each 128x32 tile = 512 16B chunks; 2/thread/array.
    const int c0 = tid, c1 = 256 + tid;
    const int r0 = c0 >> 2, j0 = c0 & 3, js0 = j0 ^ ((r0 >> 1) & 3);
    const int r1 = c1 >> 2, j1 = c1 & 3, js1 = j1 ^ ((r1 >> 1) & 3);
    const unsigned short* gA0 = Xb + (size_t)(row0 + r0) * KDIM + kbeg + js0 * 8;
    const unsigned short* gA1 = Xb + (size_t)(row0 + r1) * KDIM + kbeg + js1 * 8;
    const unsigned short* gB0 = Xb + (size_t)(col0 + r0) * KDIM + kbeg + js0 * 8;
    const unsigned short* gB1 = Xb + (size_t)(col0 + r1) * KDIM + kbeg + js1 * 8;

    f32x4 acc[4][4] = {};

#define STAGE(ph, kk)                                                          \
    do {                                                                       \
        unsigned short* b = &SH[(ph) * 8192];                                  \
        __builtin_amdgcn_global_load_lds((GLOBAL_AS void*)(void*)(gA0 + (kk)), \
                                         (LDS_AS void*)&b[c0 * 8], 16, 0, 0);  \
        __builtin_amdgcn_global_load_lds((GLOBAL_AS void*)(void*)(gA1 + (kk)), \
                                         (LDS_AS void*)&b[c1 * 8], 16, 0, 0);  \
        __builtin_amdgcn_global_load_lds((GLOBAL_AS void*)(void*)(gB0 + (kk)), \
                                         (LDS_AS void*)&b[4096 + c0 * 8], 16, 0, 0); \
        __builtin_amdgcn_global_load_lds((GLOBAL_AS void*)(void*)(gB1 + (kk)), \
                                         (LDS_AS void*)&b[4096 + c1 * 8], 16, 0, 0); \
    } while (0)

#define COMPUTE(ph)                                                            \
    do {                                                                       \
        const unsigned short* b = &SH[(ph) * 8192];                            \
        bf16x8 af[4], bq[4];                                                   \
        _Pragma("unroll")                                                      \
        for (int i = 0; i < 4; ++i)                                            \
            af[i] = *(const bf16x8*)&b[(wm + i * 16 + lr) * 32 + soff];        \
        _Pragma("unroll")                                                      \
        for (int j = 0; j < 4; ++j)                                            \
            bq[j] = *(const bf16x8*)&b[4096 + (wn + j * 16 + lr) * 32 + soff]; \
        _Pragma("unroll")                                                      \
        for (int i = 0; i < 4; ++i)                                            \
            _Pragma("unroll")                                                  \
            for (int j = 0; j < 4; ++j)                                        \
                acc[i][j] = __builtin_amdgcn_mfma_f32_16x16x32_bf16(           \
                    af[i], bq[j], acc[i][j], 0, 0, 0);                         \
    } while (0)

    STAGE(0, 0);
    STAGE(1, BK);
    STAGE(2, 2 * BK);

    int ph = 0;
    for (int k = 0; k < NITER - 2; ++k) {          // k = 0..29
        WAITCNT_VM(8);        // stage k landed; k+1,k+2 (8 loads) in flight
        block_barrier();
        COMPUTE(ph);
        block_barrier();      // all waves done reading stage k
        if (k + 3 < NITER) STAGE(ph, (k + 3) * BK);
        ph = (ph == 2) ? 0 : ph + 1;
    }
    WAITCNT_VM(4);            // stage NITER-2 landed
    block_barrier();
    COMPUTE(ph);
    block_barrier();
    ph = (ph == 2) ? 0 : ph + 1;
    WAITCNT_VM(0);            // stage NITER-1 landed
    block_barrier();
    COMPUTE(ph);
#undef STAGE
#undef COMPUTE

    // epilogue: plain bf16 partial store, layout P[tile][split][128*128].
    // C/D layout: col = lane&15, row = (lane>>4)*4 + reg.
    unsigned short* dst = P + ((size_t)blockIdx.x * SPLITK + blockIdx.y) * 16384;
    const int rbase = wm + lq * 4;
    const int cbase = wn + lr;
#pragma unroll
    for (int i = 0; i < 4; ++i)
#pragma unroll
        for (int j = 0; j < 4; ++j)
#pragma unroll
            for (int r = 0; r < 4; ++r) {
                int e = (rbase + i * 16 + r) * 128 + (cbase + j * 16);
                dst[e] = f32_to_bf16_rne(acc[i][j][r]);
            }
}

// Kernel 3: loss = (1/N^2) * sum over upper tiles of w * ((sq_i+sq_j-2g)/D)^2
// g reconstructed by summing the SPLITK bf16 partials.
__global__ __launch_bounds__(256) void loss_kernel(
        const unsigned short* __restrict__ P, const float* __restrict__ sq,
        float* __restrict__ out) {
    const float invD = 1.0f / (float)KDIM;
    const int TOT = 36 * 128 * 128;
    float acc = 0.f;
    for (int u = blockIdx.x * 256 + threadIdx.x; u < TOT; u += gridDim.x * 256) {
        int t = u >> 14;
        int e = u & 16383;
        int i = T_I[t] * 128 + (e >> 7);
        int j = T_J[t] * 128 + (e & 127);
        const unsigned short* pb = P + (size_t)t * SPLITK * 16384 + e;
        float g = 0.f;
#pragma unroll
        for (int s = 0; s < SPLITK; ++s)
            g += __uint_as_float((unsigned int)pb[s * 16384] << 16);
        float v = (sq[i] + sq[j] - 2.0f * g) * invD;
        float w = (T_I[t] == T_J[t]) ? 1.0f : 2.0f;
        acc += w * v * v;
    }
#pragma unroll
    for (int o = 32; o; o >>= 1) acc += __shfl_down(acc, o, 64);
    __shared__ float red[4];
    int lane = threadIdx.x & 63, wv = threadIdx.x >> 6;
    if (lane == 0) red[wv] = acc;
    __syncthreads();
    if (threadIdx.x == 0) {
        float total = red[0] + red[1] + red[2] + red[3];
        atomicAdd(out, total * (1.0f / ((float)N_ROWS * (float)N_ROWS)));
    }
}

extern "C" void kernel_launch(void* const* d_in, const int* in_sizes, int n_in,
                              void* d_out, int out_size, void* d_ws, size_t ws_size,
                              hipStream_t stream) {
    // d_in[0] = fm_s (dead per reference bug), d_in[1] = fm_t
    const float* fm_t = (const float*)d_in[1];
    float* out = (float*)d_out;

    // Workspace: Xb bf16 [32 MB] | P bf16 partials [18.9 MB] | sq fp32 [4 KB]
    char* ws = (char*)d_ws;
    unsigned short* Xb = (unsigned short*)ws;
    unsigned short* P  = (unsigned short*)(ws + (size_t)N_ROWS * KDIM * 2);
    float* sq = (float*)(ws + (size_t)N_ROWS * KDIM * 2
                            + (size_t)36 * SPLITK * 16384 * 2);

    hipMemsetAsync(out, 0, sizeof(float), stream);

    cast_sq_kernel<<<dim3(N_ROWS), 256, 0, stream>>>(fm_t, Xb, sq);
    gram_gemm_kernel<<<dim3(36, SPLITK), 256, 0, stream>>>(Xb, P);
    loss_kernel<<<dim3(512), 256, 0, stream>>>(P, sq, out);
}